// Round 1
// baseline (8243.409 us; speedup 1.0000x reference)
//
#include <hip/hip_runtime.h>

#define DIM   64
#define HID   256
#define TLEN  21
#define BS    65536
#define BLOCK 512
#define ROWS_PER_BLOCK (BLOCK / 2)

// tanh(x) = 1 - 2/(e^{2x}+1); clamp avoids exp overflow (tanh(10) = 1 - 4e-9).
__device__ __forceinline__ float tanh_fast(float x) {
    x = fminf(fmaxf(x, -10.0f), 10.0f);
    float e = __expf(2.0f * x);
    return 1.0f - __fdividef(2.0f, e + 1.0f);
}

// One evaluation of f(z) = tanh(z @ W1 + b1) @ W2 + b2 for this thread's
// half-row. zt[32] = this lane's 32 state components (lane pair covers 64).
// k[32] receives this lane's 32 output components.
// half = tid & 1: even lane owns dims [0,32), odd lane dims [32,64).
__device__ __forceinline__ void feval(const float* __restrict__ sW1,
                                      const float* __restrict__ sW2,
                                      const float* __restrict__ sb1,
                                      const float* __restrict__ sb2,
                                      int half,
                                      const float zt[32], float k[32])
{
    const int dbase = half << 5;   // this lane's rows of W1 / cols of output
    // init k with b2 slice
    #pragma unroll
    for (int j = 0; j < 32; j += 4) {
        float4 b = *reinterpret_cast<const float4*>(sb2 + dbase + j);
        k[j] = b.x; k[j + 1] = b.y; k[j + 2] = b.z; k[j + 3] = b.w;
    }

    for (int i8 = 0; i8 < HID; i8 += 8) {       // 8 hidden units at a time
        float dot[8];
        #pragma unroll
        for (int u = 0; u < 8; u++) dot[u] = 0.0f;

        // partial dot over this lane's 32 dims; W1 natural layout [DIM][HID]
        #pragma unroll
        for (int d = 0; d < 32; d++) {
            const float zd = zt[d];
            const float* wrow = sW1 + (dbase + d) * HID + i8;
            float4 wa = *reinterpret_cast<const float4*>(wrow);
            float4 wb = *reinterpret_cast<const float4*>(wrow + 4);
            dot[0] = fmaf(zd, wa.x, dot[0]);
            dot[1] = fmaf(zd, wa.y, dot[1]);
            dot[2] = fmaf(zd, wa.z, dot[2]);
            dot[3] = fmaf(zd, wa.w, dot[3]);
            dot[4] = fmaf(zd, wb.x, dot[4]);
            dot[5] = fmaf(zd, wb.y, dot[5]);
            dot[6] = fmaf(zd, wb.z, dot[6]);
            dot[7] = fmaf(zd, wb.w, dot[7]);
        }

        float tv[8];
        #pragma unroll
        for (int u = 0; u < 8; u++) {
            // lane-pair reduce: even lane has dims 0..31, odd lane 32..63
            float full = dot[u] + __shfl_xor(dot[u], 1, 64);
            tv[u] = tanh_fast(full + sb1[i8 + u]);
        }

        // accumulate into k: W2 natural layout [HID][DIM]
        #pragma unroll
        for (int u = 0; u < 8; u++) {
            const float ti = tv[u];
            const float* w2row = sW2 + (i8 + u) * DIM + dbase;
            #pragma unroll
            for (int j = 0; j < 32; j += 4) {
                float4 w = *reinterpret_cast<const float4*>(w2row + j);
                k[j]     = fmaf(ti, w.x, k[j]);
                k[j + 1] = fmaf(ti, w.y, k[j + 1]);
                k[j + 2] = fmaf(ti, w.z, k[j + 2]);
                k[j + 3] = fmaf(ti, w.w, k[j + 3]);
            }
        }
    }
}

__global__ __launch_bounds__(BLOCK, 2) void node_rk4_kernel(
    const float* __restrict__ z0,
    const float* __restrict__ tarr,
    const float* __restrict__ W1,
    const float* __restrict__ b1,
    const float* __restrict__ W2,
    const float* __restrict__ b2,
    float* __restrict__ out)
{
    __shared__ float sW1[DIM * HID];   // 64 KiB, natural [DIM][HID]
    __shared__ float sW2[HID * DIM];   // 64 KiB, natural [HID][DIM]
    __shared__ float sb1[HID];
    __shared__ float sb2[DIM];

    const int tid = threadIdx.x;

    // cooperative staging of weights into LDS (coalesced float4)
    for (int idx = tid; idx < DIM * HID / 4; idx += BLOCK) {
        reinterpret_cast<float4*>(sW1)[idx] = reinterpret_cast<const float4*>(W1)[idx];
        reinterpret_cast<float4*>(sW2)[idx] = reinterpret_cast<const float4*>(W2)[idx];
    }
    if (tid < HID / 4) {
        reinterpret_cast<float4*>(sb1)[tid] = reinterpret_cast<const float4*>(b1)[tid];
    } else if (tid >= 128 && tid < 128 + DIM / 4) {
        reinterpret_cast<float4*>(sb2)[tid - 128] = reinterpret_cast<const float4*>(b2)[tid - 128];
    }
    __syncthreads();

    const int row  = blockIdx.x * ROWS_PER_BLOCK + (tid >> 1);
    const int half = tid & 1;
    const int jb   = half << 5;

    // load this lane's half-row of z0
    float z[32];
    {
        const float* zp = z0 + (size_t)row * DIM + jb;
        #pragma unroll
        for (int j = 0; j < 32; j += 4) {
            float4 v = *reinterpret_cast<const float4*>(zp + j);
            z[j] = v.x; z[j + 1] = v.y; z[j + 2] = v.z; z[j + 3] = v.w;
        }
    }
    // trajectory[0] = z0
    {
        float* op = out + (size_t)row * DIM + jb;
        #pragma unroll
        for (int j = 0; j < 32; j += 4) {
            *reinterpret_cast<float4*>(op + j) = make_float4(z[j], z[j + 1], z[j + 2], z[j + 3]);
        }
    }

    float zt[32], acc[32], k[32];

    for (int s = 0; s < TLEN - 1; s++) {
        const float t0 = tarr[s];
        const float t1 = tarr[s + 1];
        const float h  = t1 - t0;

        // k1
        feval(sW1, sW2, sb1, sb2, half, z, k);
        #pragma unroll
        for (int j = 0; j < 32; j++) {
            acc[j] = k[j];
            zt[j]  = fmaf(0.5f * h, k[j], z[j]);
        }
        // k2
        feval(sW1, sW2, sb1, sb2, half, zt, k);
        #pragma unroll
        for (int j = 0; j < 32; j++) {
            acc[j] = fmaf(2.0f, k[j], acc[j]);
            zt[j]  = fmaf(0.5f * h, k[j], z[j]);
        }
        // k3
        feval(sW1, sW2, sb1, sb2, half, zt, k);
        #pragma unroll
        for (int j = 0; j < 32; j++) {
            acc[j] = fmaf(2.0f, k[j], acc[j]);
            zt[j]  = fmaf(h, k[j], z[j]);
        }
        // k4
        feval(sW1, sW2, sb1, sb2, half, zt, k);
        const float h6 = h * (1.0f / 6.0f);
        #pragma unroll
        for (int j = 0; j < 32; j++) {
            z[j] = fmaf(h6, acc[j] + k[j], z[j]);
        }

        // store trajectory[s+1]
        float* op = out + ((size_t)(s + 1) * BS + row) * DIM + jb;
        #pragma unroll
        for (int j = 0; j < 32; j += 4) {
            *reinterpret_cast<float4*>(op + j) = make_float4(z[j], z[j + 1], z[j + 2], z[j + 3]);
        }
    }
}

extern "C" void kernel_launch(void* const* d_in, const int* in_sizes, int n_in,
                              void* d_out, int out_size, void* d_ws, size_t ws_size,
                              hipStream_t stream) {
    const float* z0 = (const float*)d_in[0];
    const float* t  = (const float*)d_in[1];
    const float* W1 = (const float*)d_in[2];
    const float* b1 = (const float*)d_in[3];
    const float* W2 = (const float*)d_in[4];
    const float* b2 = (const float*)d_in[5];
    float* out = (float*)d_out;

    node_rk4_kernel<<<dim3(BS / ROWS_PER_BLOCK), dim3(BLOCK), 0, stream>>>(
        z0, t, W1, b1, W2, b2, out);
}

// Round 2
// 3709.271 us; speedup vs baseline: 2.2224x; 2.2224x over previous
//
#include <hip/hip_runtime.h>

#define DIM   64
#define HID   256
#define TLEN  21
#define BS    65536
#define BLOCK 512
#define WAVES 8
#define ROWS_PER_WAVE 32
#define ROWS_PER_BLOCK 256
#define NBLOCKS (BS / ROWS_PER_BLOCK)   // 256

typedef __bf16 bf16x8 __attribute__((ext_vector_type(8)));
typedef float  f32x16 __attribute__((ext_vector_type(16)));

union U128 { uint4 u; bf16x8 b; };

__device__ __forceinline__ bf16x8 as_bf16x8(uint4 u) { U128 t; t.u = u; return t.b; }

__device__ __forceinline__ unsigned pack2(float a, float b) {
    __bf16 x = (__bf16)a, y = (__bf16)b;
    unsigned short ux = __builtin_bit_cast(unsigned short, x);
    unsigned short uy = __builtin_bit_cast(unsigned short, y);
    return (unsigned)ux | ((unsigned)uy << 16);
}

// tanh(x) = 1 - 2/(e^{2x}+1). Saturates correctly through exp overflow:
// x>>0: e=inf -> 1-0 = 1; x<<0: e=0 -> 1-2 = -1. No clamp needed.
__device__ __forceinline__ float tanh_f(float x) {
    float e = __expf(2.0f * x);
    return 1.0f - __fdividef(2.0f, e + 1.0f);
}

// ---------------------------------------------------------------------------
// Fragment conventions (mfma_f32_32x32x16_bf16, swapped chain):
//   matmul1: D1[hid][batch] = A1(W1T) * B1(ztT)   (K = dim, 4 k-tiles of 16)
//   matmul2: D2[dim][batch] = A2(W2T) * B2(tanhT) (K = hid, 16 k-tiles of 16)
// C/D layout (m74/m101): col = lane&31, row_local = (r&3) + 8*(r>>2) + 4*(lane>>5)
// A/B frag: lane supplies slot j=0..7 -> hardware k = (lane>>5)*8 + j.
// We CHOOSE the k->physical-index map P(g,j) = 4g + (j&3) + 8*(j>>2) so that
// frag words are sequential packs of C/D regs: word w = pack(c[2w], c[2w+1]).
// Weights are stored in LDS pre-permuted with the same P => correctness free.
// ---------------------------------------------------------------------------

__device__ __forceinline__ void packB1(const float zt[DIM / 2], unsigned B1w[16]) {
    #pragma unroll
    for (int mt = 0; mt < 2; mt++)
        #pragma unroll
        for (int rh = 0; rh < 2; rh++)
            #pragma unroll
            for (int w = 0; w < 4; w++)
                B1w[(mt * 2 + rh) * 4 + w] =
                    pack2(zt[mt * 16 + rh * 8 + 2 * w], zt[mt * 16 + rh * 8 + 2 * w + 1]);
}

__device__ __forceinline__ void feval(const unsigned short* sA1,
                                      const unsigned short* sA2,
                                      const float* sb1, const float* sb2,
                                      int lane, int g,
                                      const unsigned B1w[16], float kout[32])
{
    unsigned B2w[64];
    const uint4*  A1  = reinterpret_cast<const uint4*>(sA1);
    const uint4*  A2  = reinterpret_cast<const uint4*>(sA2);
    const float4* b1q = reinterpret_cast<const float4*>(sb1);
    const float4* b2q = reinterpret_cast<const float4*>(sb2);

    #pragma unroll
    for (int ht = 0; ht < 8; ht++) {
        f32x16 d1;
        #pragma unroll
        for (int q = 0; q < 4; q++) {               // C-in = b1 fragment
            float4 bq = b1q[(ht * 2 + g) * 4 + q];  // 2-addr broadcast read
            d1[q * 4 + 0] = bq.x; d1[q * 4 + 1] = bq.y;
            d1[q * 4 + 2] = bq.z; d1[q * 4 + 3] = bq.w;
        }
        #pragma unroll
        for (int kt = 0; kt < 4; kt++) {
            bf16x8 a = as_bf16x8(A1[(ht * 4 + kt) * 64 + lane]);
            uint4 bu = make_uint4(B1w[kt * 4 + 0], B1w[kt * 4 + 1],
                                  B1w[kt * 4 + 2], B1w[kt * 4 + 3]);
            d1 = __builtin_amdgcn_mfma_f32_32x32x16_bf16(a, as_bf16x8(bu), d1, 0, 0, 0);
        }
        // tanh + pack: D1 regs 0..7 -> k-tile 2ht, regs 8..15 -> k-tile 2ht+1
        #pragma unroll
        for (int w = 0; w < 4; w++) {
            B2w[(2 * ht) * 4 + w]     = pack2(tanh_f(d1[2 * w]),     tanh_f(d1[2 * w + 1]));
            B2w[(2 * ht + 1) * 4 + w] = pack2(tanh_f(d1[8 + 2 * w]), tanh_f(d1[8 + 2 * w + 1]));
        }
    }

    #pragma unroll
    for (int mt = 0; mt < 2; mt++) {
        f32x16 d2;
        #pragma unroll
        for (int q = 0; q < 4; q++) {               // C-in = b2 fragment
            float4 bq = b2q[(mt * 2 + g) * 4 + q];
            d2[q * 4 + 0] = bq.x; d2[q * 4 + 1] = bq.y;
            d2[q * 4 + 2] = bq.z; d2[q * 4 + 3] = bq.w;
        }
        #pragma unroll
        for (int kt2 = 0; kt2 < 16; kt2++) {
            bf16x8 a = as_bf16x8(A2[(mt * 16 + kt2) * 64 + lane]);
            uint4 bu = make_uint4(B2w[kt2 * 4 + 0], B2w[kt2 * 4 + 1],
                                  B2w[kt2 * 4 + 2], B2w[kt2 * 4 + 3]);
            d2 = __builtin_amdgcn_mfma_f32_32x32x16_bf16(a, as_bf16x8(bu), d2, 0, 0, 0);
        }
        #pragma unroll
        for (int r = 0; r < 16; r++) kout[mt * 16 + r] = d2[r];
    }
}

extern "C" __global__ __launch_bounds__(BLOCK, 2) void node_mfma_kernel(
    const float* __restrict__ z0, const float* __restrict__ tarr,
    const float* __restrict__ W1, const float* __restrict__ b1,
    const float* __restrict__ W2, const float* __restrict__ b2,
    float* __restrict__ out)
{
    __shared__ __align__(16) unsigned short sA1[32 * 64 * 8];  // 32 KiB [ht*4+kt][lane][j]
    __shared__ __align__(16) unsigned short sA2[32 * 64 * 8];  // 32 KiB [mt*16+kt2][lane][j]
    __shared__ __align__(16) float sb1[8 * 2 * 16];            // [ht][g][r]
    __shared__ __align__(16) float sb2[2 * 2 * 16];            // [mt][g][r]
    __shared__ __align__(16) float trbuf[WAVES][2048];         // 8 KiB per wave

    const int tid  = threadIdx.x;
    const int lane = tid & 63;
    const int wv   = tid >> 6;
    const int g    = lane >> 5;
    const int ln31 = lane & 31;

    // ---- stage W1 fragments (pre-permuted, bf16) ----
    for (int idx = tid; idx < 16384; idx += BLOCK) {
        int l = idx & 63, rest = idx >> 6;
        int j = rest & 7, kt = (rest >> 3) & 3, ht = rest >> 5;
        int gg  = l >> 5;
        int dim = kt * 16 + 4 * gg + (j & 3) + 8 * (j >> 2);
        int hid = ht * 32 + (l & 31);
        __bf16 bv = (__bf16)W1[dim * HID + hid];
        sA1[((ht * 4 + kt) * 64 + l) * 8 + j] = __builtin_bit_cast(unsigned short, bv);
    }
    // ---- stage W2 fragments ----
    for (int idx = tid; idx < 16384; idx += BLOCK) {
        int l = idx & 63, rest = idx >> 6;
        int j = rest & 7, kt2 = (rest >> 3) & 15, mt = rest >> 7;
        int gg  = l >> 5;
        int hid = kt2 * 16 + 4 * gg + (j & 3) + 8 * (j >> 2);
        int dim = mt * 32 + (l & 31);
        __bf16 bv = (__bf16)W2[hid * DIM + dim];
        sA2[((mt * 16 + kt2) * 64 + l) * 8 + j] = __builtin_bit_cast(unsigned short, bv);
    }
    // ---- biases, permuted to C/D reg order ----
    if (tid < 256) {
        int r = tid & 15, gg = (tid >> 4) & 1, ht = tid >> 5;
        sb1[tid] = b1[ht * 32 + (r & 3) + 8 * (r >> 2) + 4 * gg];
    }
    if (tid < 64) {
        int r = tid & 15, gg = (tid >> 4) & 1, mt = tid >> 5;
        sb2[tid] = b2[mt * 32 + (r & 3) + 8 * (r >> 2) + 4 * gg];
    }

    // ---- out[0] = z0 (coalesced block-slice copy) ----
    {
        const float4* src = reinterpret_cast<const float4*>(z0 + (size_t)blockIdx.x * ROWS_PER_BLOCK * DIM);
        float4*       dst = reinterpret_cast<float4*>(out + (size_t)blockIdx.x * ROWS_PER_BLOCK * DIM);
        for (int i = tid; i < ROWS_PER_BLOCK * DIM / 4; i += BLOCK) dst[i] = src[i];
    }

    __syncthreads();

    const int rowbase = blockIdx.x * ROWS_PER_BLOCK + wv * ROWS_PER_WAVE;
    float* tb = trbuf[wv];

    // ---- z0 -> registers via per-wave LDS transpose (XOR-swizzled 16B) ----
    #pragma unroll
    for (int p = 0; p < 8; p++) {
        int batch  = (lane >> 4) + 4 * p;
        int linear = lane * 16 + p * 1024;
        float4 v = *reinterpret_cast<const float4*>(
            z0 + (size_t)(rowbase + batch) * DIM + (lane & 15) * 4);
        *reinterpret_cast<float4*>((char*)tb + (linear ^ ((batch & 7) << 4))) = v;
    }
    asm volatile("s_waitcnt lgkmcnt(0)" ::: "memory");

    float z[32];
    #pragma unroll
    for (int mt = 0; mt < 2; mt++)
        #pragma unroll
        for (int rp = 0; rp < 8; rp++) {
            int d    = mt * 32 + (rp & 1) * 2 + 8 * (rp >> 1) + 4 * g;  // r = 2*rp
            int byte = ln31 * 256 + d * 4;
            float2 v = *reinterpret_cast<float2*>((char*)tb + (byte ^ ((ln31 & 7) << 4)));
            z[mt * 16 + rp * 2]     = v.x;
            z[mt * 16 + rp * 2 + 1] = v.y;
        }

    float acc[32], kreg[32], zt[32];
    unsigned B1w[16];

    for (int s = 0; s < TLEN - 1; s++) {
        float t0 = tarr[s];
        float h  = tarr[s + 1] - t0;

        packB1(z, B1w);
        feval(sA1, sA2, sb1, sb2, lane, g, B1w, kreg);       // k1
        #pragma unroll
        for (int i = 0; i < 32; i++) {
            acc[i] = kreg[i];
            zt[i]  = fmaf(0.5f * h, kreg[i], z[i]);
        }
        packB1(zt, B1w);
        feval(sA1, sA2, sb1, sb2, lane, g, B1w, kreg);       // k2
        #pragma unroll
        for (int i = 0; i < 32; i++) {
            acc[i] = fmaf(2.0f, kreg[i], acc[i]);
            zt[i]  = fmaf(0.5f * h, kreg[i], z[i]);
        }
        packB1(zt, B1w);
        feval(sA1, sA2, sb1, sb2, lane, g, B1w, kreg);       // k3
        #pragma unroll
        for (int i = 0; i < 32; i++) {
            acc[i] = fmaf(2.0f, kreg[i], acc[i]);
            zt[i]  = fmaf(h, kreg[i], z[i]);
        }
        packB1(zt, B1w);
        feval(sA1, sA2, sb1, sb2, lane, g, B1w, kreg);       // k4
        const float h6 = h * (1.0f / 6.0f);
        #pragma unroll
        for (int i = 0; i < 32; i++)
            z[i] = fmaf(h6, acc[i] + kreg[i], z[i]);

        // ---- store trajectory[s+1] via per-wave LDS transpose ----
        asm volatile("s_waitcnt lgkmcnt(0)" ::: "memory");
        #pragma unroll
        for (int mt = 0; mt < 2; mt++)
            #pragma unroll
            for (int rp = 0; rp < 8; rp++) {
                int d    = mt * 32 + (rp & 1) * 2 + 8 * (rp >> 1) + 4 * g;
                int byte = ln31 * 256 + d * 4;
                float2 v = make_float2(z[mt * 16 + rp * 2], z[mt * 16 + rp * 2 + 1]);
                *reinterpret_cast<float2*>((char*)tb + (byte ^ ((ln31 & 7) << 4))) = v;
            }
        asm volatile("s_waitcnt lgkmcnt(0)" ::: "memory");
        float* obase = out + ((size_t)(s + 1) * BS + rowbase) * DIM;
        #pragma unroll
        for (int p = 0; p < 8; p++) {
            int batch  = (lane >> 4) + 4 * p;
            int linear = lane * 16 + p * 1024;
            float4 v = *reinterpret_cast<float4*>((char*)tb + (linear ^ ((batch & 7) << 4)));
            *reinterpret_cast<float4*>(obase + batch * DIM + (lane & 15) * 4) = v;
        }
    }
}

extern "C" void kernel_launch(void* const* d_in, const int* in_sizes, int n_in,
                              void* d_out, int out_size, void* d_ws, size_t ws_size,
                              hipStream_t stream) {
    const float* z0 = (const float*)d_in[0];
    const float* t  = (const float*)d_in[1];
    const float* W1 = (const float*)d_in[2];
    const float* b1 = (const float*)d_in[3];
    const float* W2 = (const float*)d_in[4];
    const float* b2 = (const float*)d_in[5];
    float* out = (float*)d_out;

    node_mfma_kernel<<<dim3(NBLOCKS), dim3(BLOCK), 0, stream>>>(
        z0, t, W1, b1, W2, b2, out);
}

// Round 3
// 3426.986 us; speedup vs baseline: 2.4054x; 1.0824x over previous
//
#include <hip/hip_runtime.h>

#define DIM   64
#define HID   256
#define TLEN  21
#define BS    65536
#define BLOCK 512
#define WAVES 8
#define ROWS_PER_WAVE 32
#define ROWS_PER_BLOCK 256
#define NBLOCKS (BS / ROWS_PER_BLOCK)   // 256

typedef __bf16 bf16x8 __attribute__((ext_vector_type(8)));
typedef float  f32x16 __attribute__((ext_vector_type(16)));

union U128 { uint4 u; bf16x8 b; };

__device__ __forceinline__ bf16x8 as_bf16x8(uint4 u) { U128 t; t.u = u; return t.b; }

__device__ __forceinline__ unsigned pack2(float a, float b) {
    __bf16 x = (__bf16)a, y = (__bf16)b;
    unsigned short ux = __builtin_bit_cast(unsigned short, x);
    unsigned short uy = __builtin_bit_cast(unsigned short, y);
    return (unsigned)ux | ((unsigned)uy << 16);
}

// tanh(x) = 1 - 2/(e^{2x}+1). Saturates correctly through exp overflow.
__device__ __forceinline__ float tanh_f(float x) {
    float e = __expf(2.0f * x);
    return 1.0f - __fdividef(2.0f, e + 1.0f);
}

// ---------------------------------------------------------------------------
// Fragment conventions (mfma_f32_32x32x16_bf16, swapped chain) — verified in
// round 2 (absmax 0.031):
//   matmul1: D1[hid][batch] = A1(W1T) * B1(ztT)   (K = dim, 4 k-tiles)
//   matmul2: D2[dim][batch] = A2(W2T) * B2(tanhT) (K = hid, 16 k-tiles)
// C/D layout: col = lane&31, row_local = (r&3) + 8*(r>>2) + 4*(lane>>5).
// B-frag k->physical map chosen as P(g,j) = 4g + (j&3) + 8*(j>>2) so that
// frag word i = pack2(x[2i], x[2i+1]) with x in C/D register order; weights
// pre-permuted in LDS with the same P.
//
// Round-3 restructure: matmul2 accumulates INSIDE the ht loop (B2 live words
// 64 -> 8), zt/acc arrays eliminated (fused axpy-pack + running zf) to kill
// the scratch spills that dominated round 2.
// ---------------------------------------------------------------------------

// B1w[i] = pack2(z[2i] + c*k[2i], z[2i+1] + c*k[2i+1])
__device__ __forceinline__ void packB1_axpy(const float z[32], const float k[32],
                                            float c, unsigned B1w[16]) {
    #pragma unroll
    for (int i = 0; i < 16; i++)
        B1w[i] = pack2(fmaf(c, k[2 * i], z[2 * i]),
                       fmaf(c, k[2 * i + 1], z[2 * i + 1]));
}

__device__ __forceinline__ void feval(const unsigned short* sA1,
                                      const unsigned short* sA2,
                                      const float* sb1, const float* sb2,
                                      int lane, int g,
                                      const unsigned B1w[16], float kout[32])
{
    const uint4*  A1  = reinterpret_cast<const uint4*>(sA1);
    const uint4*  A2  = reinterpret_cast<const uint4*>(sA2);
    const float4* b1q = reinterpret_cast<const float4*>(sb1);
    const float4* b2q = reinterpret_cast<const float4*>(sb2);

    f32x16 d2a, d2b;                               // running dim-output tiles
    #pragma unroll
    for (int q = 0; q < 4; q++) {
        float4 ba = b2q[(0 * 2 + g) * 4 + q];
        float4 bb = b2q[(1 * 2 + g) * 4 + q];
        d2a[q * 4 + 0] = ba.x; d2a[q * 4 + 1] = ba.y;
        d2a[q * 4 + 2] = ba.z; d2a[q * 4 + 3] = ba.w;
        d2b[q * 4 + 0] = bb.x; d2b[q * 4 + 1] = bb.y;
        d2b[q * 4 + 2] = bb.z; d2b[q * 4 + 3] = bb.w;
    }

    #pragma unroll
    for (int ht = 0; ht < 8; ht++) {
        f32x16 d1;
        #pragma unroll
        for (int q = 0; q < 4; q++) {              // C-in = b1 fragment
            float4 bq = b1q[(ht * 2 + g) * 4 + q];
            d1[q * 4 + 0] = bq.x; d1[q * 4 + 1] = bq.y;
            d1[q * 4 + 2] = bq.z; d1[q * 4 + 3] = bq.w;
        }
        #pragma unroll
        for (int kt = 0; kt < 4; kt++) {
            bf16x8 a = as_bf16x8(A1[(ht * 4 + kt) * 64 + lane]);
            uint4 bu = make_uint4(B1w[kt * 4 + 0], B1w[kt * 4 + 1],
                                  B1w[kt * 4 + 2], B1w[kt * 4 + 3]);
            d1 = __builtin_amdgcn_mfma_f32_32x32x16_bf16(a, as_bf16x8(bu), d1, 0, 0, 0);
        }
        // tanh + pack: regs 0..7 -> k-tile 2ht, regs 8..15 -> k-tile 2ht+1;
        // feed matmul2 immediately (no B2 array).
        uint4 lo = make_uint4(pack2(tanh_f(d1[0]), tanh_f(d1[1])),
                              pack2(tanh_f(d1[2]), tanh_f(d1[3])),
                              pack2(tanh_f(d1[4]), tanh_f(d1[5])),
                              pack2(tanh_f(d1[6]), tanh_f(d1[7])));
        uint4 hi = make_uint4(pack2(tanh_f(d1[8]),  tanh_f(d1[9])),
                              pack2(tanh_f(d1[10]), tanh_f(d1[11])),
                              pack2(tanh_f(d1[12]), tanh_f(d1[13])),
                              pack2(tanh_f(d1[14]), tanh_f(d1[15])));
        d2a = __builtin_amdgcn_mfma_f32_32x32x16_bf16(
                  as_bf16x8(A2[(0 * 16 + 2 * ht) * 64 + lane]), as_bf16x8(lo), d2a, 0, 0, 0);
        d2b = __builtin_amdgcn_mfma_f32_32x32x16_bf16(
                  as_bf16x8(A2[(1 * 16 + 2 * ht) * 64 + lane]), as_bf16x8(lo), d2b, 0, 0, 0);
        d2a = __builtin_amdgcn_mfma_f32_32x32x16_bf16(
                  as_bf16x8(A2[(0 * 16 + 2 * ht + 1) * 64 + lane]), as_bf16x8(hi), d2a, 0, 0, 0);
        d2b = __builtin_amdgcn_mfma_f32_32x32x16_bf16(
                  as_bf16x8(A2[(1 * 16 + 2 * ht + 1) * 64 + lane]), as_bf16x8(hi), d2b, 0, 0, 0);
    }

    #pragma unroll
    for (int r = 0; r < 16; r++) { kout[r] = d2a[r]; kout[16 + r] = d2b[r]; }
}

extern "C" __global__ __launch_bounds__(BLOCK, 2) void node_mfma_kernel(
    const float* __restrict__ z0, const float* __restrict__ tarr,
    const float* __restrict__ W1, const float* __restrict__ b1,
    const float* __restrict__ W2, const float* __restrict__ b2,
    float* __restrict__ out)
{
    __shared__ __align__(16) unsigned short sA1[32 * 64 * 8];  // 32 KiB
    __shared__ __align__(16) unsigned short sA2[32 * 64 * 8];  // 32 KiB
    __shared__ __align__(16) float sb1[8 * 2 * 16];
    __shared__ __align__(16) float sb2[2 * 2 * 16];
    __shared__ __align__(16) float trbuf[WAVES][2048];         // 8 KiB per wave

    const int tid  = threadIdx.x;
    const int lane = tid & 63;
    const int wv   = tid >> 6;
    const int g    = lane >> 5;
    const int ln31 = lane & 31;

    // ---- stage W1 fragments (pre-permuted, bf16) ----
    for (int idx = tid; idx < 16384; idx += BLOCK) {
        int l = idx & 63, rest = idx >> 6;
        int j = rest & 7, kt = (rest >> 3) & 3, ht = rest >> 5;
        int gg  = l >> 5;
        int dim = kt * 16 + 4 * gg + (j & 3) + 8 * (j >> 2);
        int hid = ht * 32 + (l & 31);
        __bf16 bv = (__bf16)W1[dim * HID + hid];
        sA1[((ht * 4 + kt) * 64 + l) * 8 + j] = __builtin_bit_cast(unsigned short, bv);
    }
    // ---- stage W2 fragments ----
    for (int idx = tid; idx < 16384; idx += BLOCK) {
        int l = idx & 63, rest = idx >> 6;
        int j = rest & 7, kt2 = (rest >> 3) & 15, mt = rest >> 7;
        int gg  = l >> 5;
        int hid = kt2 * 16 + 4 * gg + (j & 3) + 8 * (j >> 2);
        int dim = mt * 32 + (l & 31);
        __bf16 bv = (__bf16)W2[hid * DIM + dim];
        sA2[((mt * 16 + kt2) * 64 + l) * 8 + j] = __builtin_bit_cast(unsigned short, bv);
    }
    // ---- biases, permuted to C/D reg order ----
    if (tid < 256) {
        int r = tid & 15, gg = (tid >> 4) & 1, ht = tid >> 5;
        sb1[tid] = b1[ht * 32 + (r & 3) + 8 * (r >> 2) + 4 * gg];
    }
    if (tid < 64) {
        int r = tid & 15, gg = (tid >> 4) & 1, mt = tid >> 5;
        sb2[tid] = b2[mt * 32 + (r & 3) + 8 * (r >> 2) + 4 * gg];
    }

    // ---- out[0] = z0 (coalesced block-slice copy) ----
    {
        const float4* src = reinterpret_cast<const float4*>(z0 + (size_t)blockIdx.x * ROWS_PER_BLOCK * DIM);
        float4*       dst = reinterpret_cast<float4*>(out + (size_t)blockIdx.x * ROWS_PER_BLOCK * DIM);
        for (int i = tid; i < ROWS_PER_BLOCK * DIM / 4; i += BLOCK) dst[i] = src[i];
    }

    __syncthreads();

    const int rowbase = blockIdx.x * ROWS_PER_BLOCK + wv * ROWS_PER_WAVE;
    float* tb = trbuf[wv];

    // ---- z0 -> registers via per-wave LDS transpose (XOR-swizzled 16B) ----
    #pragma unroll
    for (int p = 0; p < 8; p++) {
        int batch  = (lane >> 4) + 4 * p;
        int linear = lane * 16 + p * 1024;
        float4 v = *reinterpret_cast<const float4*>(
            z0 + (size_t)(rowbase + batch) * DIM + (lane & 15) * 4);
        *reinterpret_cast<float4*>((char*)tb + (linear ^ ((batch & 7) << 4))) = v;
    }
    asm volatile("s_waitcnt lgkmcnt(0)" ::: "memory");

    float z[32];
    #pragma unroll
    for (int mt = 0; mt < 2; mt++)
        #pragma unroll
        for (int rp = 0; rp < 8; rp++) {
            int d    = mt * 32 + (rp & 1) * 2 + 8 * (rp >> 1) + 4 * g;  // r = 2*rp
            int byte = ln31 * 256 + d * 4;
            float2 v = *reinterpret_cast<float2*>((char*)tb + (byte ^ ((ln31 & 7) << 4)));
            z[mt * 16 + rp * 2]     = v.x;
            z[mt * 16 + rp * 2 + 1] = v.y;
        }

    float zf[32], k[32];
    unsigned B1w[16];

    for (int s = 0; s < TLEN - 1; s++) {
        const float t0 = tarr[s];
        const float h  = tarr[s + 1] - t0;
        const float h6 = h * (1.0f / 6.0f);
        const float h3 = h * (1.0f / 3.0f);

        // k1: B1 from z directly
        #pragma unroll
        for (int i = 0; i < 16; i++) B1w[i] = pack2(z[2 * i], z[2 * i + 1]);
        feval(sA1, sA2, sb1, sb2, lane, g, B1w, k);
        #pragma unroll
        for (int i = 0; i < 32; i++) zf[i] = fmaf(h6, k[i], z[i]);

        packB1_axpy(z, k, 0.5f * h, B1w);
        feval(sA1, sA2, sb1, sb2, lane, g, B1w, k);          // k2
        #pragma unroll
        for (int i = 0; i < 32; i++) zf[i] = fmaf(h3, k[i], zf[i]);

        packB1_axpy(z, k, 0.5f * h, B1w);
        feval(sA1, sA2, sb1, sb2, lane, g, B1w, k);          // k3
        #pragma unroll
        for (int i = 0; i < 32; i++) zf[i] = fmaf(h3, k[i], zf[i]);

        packB1_axpy(z, k, h, B1w);
        feval(sA1, sA2, sb1, sb2, lane, g, B1w, k);          // k4
        #pragma unroll
        for (int i = 0; i < 32; i++) z[i] = fmaf(h6, k[i], zf[i]);

        // ---- store trajectory[s+1] via per-wave LDS transpose ----
        asm volatile("s_waitcnt lgkmcnt(0)" ::: "memory");
        #pragma unroll
        for (int mt = 0; mt < 2; mt++)
            #pragma unroll
            for (int rp = 0; rp < 8; rp++) {
                int d    = mt * 32 + (rp & 1) * 2 + 8 * (rp >> 1) + 4 * g;
                int byte = ln31 * 256 + d * 4;
                float2 v = make_float2(z[mt * 16 + rp * 2], z[mt * 16 + rp * 2 + 1]);
                *reinterpret_cast<float2*>((char*)tb + (byte ^ ((ln31 & 7) << 4))) = v;
            }
        asm volatile("s_waitcnt lgkmcnt(0)" ::: "memory");
        float* obase = out + ((size_t)(s + 1) * BS + rowbase) * DIM;
        #pragma unroll
        for (int p = 0; p < 8; p++) {
            int batch  = (lane >> 4) + 4 * p;
            int linear = lane * 16 + p * 1024;
            float4 v = *reinterpret_cast<float4*>((char*)tb + (linear ^ ((batch & 7) << 4)));
            *reinterpret_cast<float4*>(obase + batch * DIM + (lane & 15) * 4) = v;
        }
    }
}

extern "C" void kernel_launch(void* const* d_in, const int* in_sizes, int n_in,
                              void* d_out, int out_size, void* d_ws, size_t ws_size,
                              hipStream_t stream) {
    const float* z0 = (const float*)d_in[0];
    const float* t  = (const float*)d_in[1];
    const float* W1 = (const float*)d_in[2];
    const float* b1 = (const float*)d_in[3];
    const float* W2 = (const float*)d_in[4];
    const float* b2 = (const float*)d_in[5];
    float* out = (float*)d_out;

    node_mfma_kernel<<<dim3(NBLOCKS), dim3(BLOCK), 0, stream>>>(
        z0, t, W1, b1, W2, b2, out);
}

// Round 4
// 3278.236 us; speedup vs baseline: 2.5146x; 1.0454x over previous
//
#include <hip/hip_runtime.h>

#define DIM   64
#define HID   256
#define TLEN  21
#define BS    65536
#define BLOCK 512
#define WAVES 8
#define ROWS_PER_WAVE 32
#define ROWS_PER_BLOCK 256
#define NBLOCKS (BS / ROWS_PER_BLOCK)   // 256

typedef __bf16 bf16x8 __attribute__((ext_vector_type(8)));
typedef float  f32x16 __attribute__((ext_vector_type(16)));

union U128 { uint4 u; bf16x8 b; };

__device__ __forceinline__ bf16x8 as_bf16x8(uint4 u) { U128 t; t.u = u; return t.b; }

__device__ __forceinline__ unsigned pack2(float a, float b) {
    __bf16 x = (__bf16)a, y = (__bf16)b;
    unsigned short ux = __builtin_bit_cast(unsigned short, x);
    unsigned short uy = __builtin_bit_cast(unsigned short, y);
    return (unsigned)ux | ((unsigned)uy << 16);
}

// tanh(x) = 1 - 2/(e^{2x}+1). Saturates correctly through exp overflow.
__device__ __forceinline__ float tanh_f(float x) {
    float e = __expf(2.0f * x);
    return 1.0f - __fdividef(2.0f, e + 1.0f);
}

// ---------------------------------------------------------------------------
// Fragment conventions (mfma_f32_32x32x16_bf16, swapped chain) — verified
// (absmax 0.031):
//   matmul1: D1[hid][batch] = A1(W1T) * B1(ztT)   (K = dim, 4 k-tiles)
//   matmul2: D2[dim][batch] = A2(W2T) * B2(tanhT) (K = hid, 16 k-tiles)
// C/D layout: col = lane&31, row_local = (r&3) + 8*(r>>2) + 4*(lane>>5).
// B-frag k->physical map P(g,j) = 4g + (j&3) + 8*(j>>2) so frag word i =
// pack2(x[2i], x[2i+1]) in C/D register order; weights pre-permuted in LDS.
//
// Round-4 change: __launch_bounds__(512, 1). Rounds 2-3 used (512, 2) which
// capped the allocator at 128 VGPRs (4 waves/SIMD budget) -> ~10 GB of
// scratch spill traffic = the whole runtime. LDS (129.5 KB) limits us to
// 1 block/CU anyway, so (512,1) = 256-VGPR budget at identical occupancy.
// ---------------------------------------------------------------------------

// B1w[i] = pack2(z[2i] + c*k[2i], z[2i+1] + c*k[2i+1])
__device__ __forceinline__ void packB1_axpy(const float z[32], const float k[32],
                                            float c, unsigned B1w[16]) {
    #pragma unroll
    for (int i = 0; i < 16; i++)
        B1w[i] = pack2(fmaf(c, k[2 * i], z[2 * i]),
                       fmaf(c, k[2 * i + 1], z[2 * i + 1]));
}

__device__ __forceinline__ void feval(const unsigned short* sA1,
                                      const unsigned short* sA2,
                                      const float* sb1, const float* sb2,
                                      int lane, int g,
                                      const unsigned B1w[16], float kout[32])
{
    const uint4*  A1  = reinterpret_cast<const uint4*>(sA1);
    const uint4*  A2  = reinterpret_cast<const uint4*>(sA2);
    const float4* b1q = reinterpret_cast<const float4*>(sb1);
    const float4* b2q = reinterpret_cast<const float4*>(sb2);

    f32x16 d2a, d2b;                               // running dim-output tiles
    #pragma unroll
    for (int q = 0; q < 4; q++) {
        float4 ba = b2q[(0 * 2 + g) * 4 + q];
        float4 bb = b2q[(1 * 2 + g) * 4 + q];
        d2a[q * 4 + 0] = ba.x; d2a[q * 4 + 1] = ba.y;
        d2a[q * 4 + 2] = ba.z; d2a[q * 4 + 3] = ba.w;
        d2b[q * 4 + 0] = bb.x; d2b[q * 4 + 1] = bb.y;
        d2b[q * 4 + 2] = bb.z; d2b[q * 4 + 3] = bb.w;
    }

    #pragma unroll
    for (int ht = 0; ht < 8; ht++) {
        f32x16 d1;
        #pragma unroll
        for (int q = 0; q < 4; q++) {              // C-in = b1 fragment
            float4 bq = b1q[(ht * 2 + g) * 4 + q];
            d1[q * 4 + 0] = bq.x; d1[q * 4 + 1] = bq.y;
            d1[q * 4 + 2] = bq.z; d1[q * 4 + 3] = bq.w;
        }
        #pragma unroll
        for (int kt = 0; kt < 4; kt++) {
            bf16x8 a = as_bf16x8(A1[(ht * 4 + kt) * 64 + lane]);
            uint4 bu = make_uint4(B1w[kt * 4 + 0], B1w[kt * 4 + 1],
                                  B1w[kt * 4 + 2], B1w[kt * 4 + 3]);
            d1 = __builtin_amdgcn_mfma_f32_32x32x16_bf16(a, as_bf16x8(bu), d1, 0, 0, 0);
        }
        // tanh + pack: regs 0..7 -> k-tile 2ht, regs 8..15 -> k-tile 2ht+1;
        // feed matmul2 immediately (no B2 array).
        uint4 lo = make_uint4(pack2(tanh_f(d1[0]), tanh_f(d1[1])),
                              pack2(tanh_f(d1[2]), tanh_f(d1[3])),
                              pack2(tanh_f(d1[4]), tanh_f(d1[5])),
                              pack2(tanh_f(d1[6]), tanh_f(d1[7])));
        uint4 hi = make_uint4(pack2(tanh_f(d1[8]),  tanh_f(d1[9])),
                              pack2(tanh_f(d1[10]), tanh_f(d1[11])),
                              pack2(tanh_f(d1[12]), tanh_f(d1[13])),
                              pack2(tanh_f(d1[14]), tanh_f(d1[15])));
        d2a = __builtin_amdgcn_mfma_f32_32x32x16_bf16(
                  as_bf16x8(A2[(0 * 16 + 2 * ht) * 64 + lane]), as_bf16x8(lo), d2a, 0, 0, 0);
        d2b = __builtin_amdgcn_mfma_f32_32x32x16_bf16(
                  as_bf16x8(A2[(1 * 16 + 2 * ht) * 64 + lane]), as_bf16x8(lo), d2b, 0, 0, 0);
        d2a = __builtin_amdgcn_mfma_f32_32x32x16_bf16(
                  as_bf16x8(A2[(0 * 16 + 2 * ht + 1) * 64 + lane]), as_bf16x8(hi), d2a, 0, 0, 0);
        d2b = __builtin_amdgcn_mfma_f32_32x32x16_bf16(
                  as_bf16x8(A2[(1 * 16 + 2 * ht + 1) * 64 + lane]), as_bf16x8(hi), d2b, 0, 0, 0);
    }

    #pragma unroll
    for (int r = 0; r < 16; r++) { kout[r] = d2a[r]; kout[16 + r] = d2b[r]; }
}

extern "C" __global__ __launch_bounds__(BLOCK, 1) void node_mfma_kernel(
    const float* __restrict__ z0, const float* __restrict__ tarr,
    const float* __restrict__ W1, const float* __restrict__ b1,
    const float* __restrict__ W2, const float* __restrict__ b2,
    float* __restrict__ out)
{
    __shared__ __align__(16) unsigned short sA1[32 * 64 * 8];  // 32 KiB
    __shared__ __align__(16) unsigned short sA2[32 * 64 * 8];  // 32 KiB
    __shared__ __align__(16) float sb1[8 * 2 * 16];
    __shared__ __align__(16) float sb2[2 * 2 * 16];
    __shared__ __align__(16) float trbuf[WAVES][2048];         // 8 KiB per wave

    const int tid  = threadIdx.x;
    const int lane = tid & 63;
    const int wv   = tid >> 6;
    const int g    = lane >> 5;
    const int ln31 = lane & 31;

    // ---- stage W1 fragments (pre-permuted, bf16) ----
    for (int idx = tid; idx < 16384; idx += BLOCK) {
        int l = idx & 63, rest = idx >> 6;
        int j = rest & 7, kt = (rest >> 3) & 3, ht = rest >> 5;
        int gg  = l >> 5;
        int dim = kt * 16 + 4 * gg + (j & 3) + 8 * (j >> 2);
        int hid = ht * 32 + (l & 31);
        __bf16 bv = (__bf16)W1[dim * HID + hid];
        sA1[((ht * 4 + kt) * 64 + l) * 8 + j] = __builtin_bit_cast(unsigned short, bv);
    }
    // ---- stage W2 fragments ----
    for (int idx = tid; idx < 16384; idx += BLOCK) {
        int l = idx & 63, rest = idx >> 6;
        int j = rest & 7, kt2 = (rest >> 3) & 15, mt = rest >> 7;
        int gg  = l >> 5;
        int hid = kt2 * 16 + 4 * gg + (j & 3) + 8 * (j >> 2);
        int dim = mt * 32 + (l & 31);
        __bf16 bv = (__bf16)W2[hid * DIM + dim];
        sA2[((mt * 16 + kt2) * 64 + l) * 8 + j] = __builtin_bit_cast(unsigned short, bv);
    }
    // ---- biases, permuted to C/D reg order ----
    if (tid < 256) {
        int r = tid & 15, gg = (tid >> 4) & 1, ht = tid >> 5;
        sb1[tid] = b1[ht * 32 + (r & 3) + 8 * (r >> 2) + 4 * gg];
    }
    if (tid < 64) {
        int r = tid & 15, gg = (tid >> 4) & 1, mt = tid >> 5;
        sb2[tid] = b2[mt * 32 + (r & 3) + 8 * (r >> 2) + 4 * gg];
    }

    // ---- out[0] = z0 (coalesced block-slice copy) ----
    {
        const float4* src = reinterpret_cast<const float4*>(z0 + (size_t)blockIdx.x * ROWS_PER_BLOCK * DIM);
        float4*       dst = reinterpret_cast<float4*>(out + (size_t)blockIdx.x * ROWS_PER_BLOCK * DIM);
        for (int i = tid; i < ROWS_PER_BLOCK * DIM / 4; i += BLOCK) dst[i] = src[i];
    }

    __syncthreads();

    const int rowbase = blockIdx.x * ROWS_PER_BLOCK + wv * ROWS_PER_WAVE;
    float* tb = trbuf[wv];

    // ---- z0 -> registers via per-wave LDS transpose (XOR-swizzled 16B) ----
    #pragma unroll
    for (int p = 0; p < 8; p++) {
        int batch  = (lane >> 4) + 4 * p;
        int linear = lane * 16 + p * 1024;
        float4 v = *reinterpret_cast<const float4*>(
            z0 + (size_t)(rowbase + batch) * DIM + (lane & 15) * 4);
        *reinterpret_cast<float4*>((char*)tb + (linear ^ ((batch & 7) << 4))) = v;
    }
    asm volatile("s_waitcnt lgkmcnt(0)" ::: "memory");

    float z[32];
    #pragma unroll
    for (int mt = 0; mt < 2; mt++)
        #pragma unroll
        for (int rp = 0; rp < 8; rp++) {
            int d    = mt * 32 + (rp & 1) * 2 + 8 * (rp >> 1) + 4 * g;  // r = 2*rp
            int byte = ln31 * 256 + d * 4;
            float2 v = *reinterpret_cast<float2*>((char*)tb + (byte ^ ((ln31 & 7) << 4)));
            z[mt * 16 + rp * 2]     = v.x;
            z[mt * 16 + rp * 2 + 1] = v.y;
        }

    float zf[32], k[32];
    unsigned B1w[16];

    for (int s = 0; s < TLEN - 1; s++) {
        const float h  = tarr[s + 1] - tarr[s];
        const float h6 = h * (1.0f / 6.0f);
        const float h3 = h * (1.0f / 3.0f);

        // k1: B1 from z directly
        #pragma unroll
        for (int i = 0; i < 16; i++) B1w[i] = pack2(z[2 * i], z[2 * i + 1]);
        feval(sA1, sA2, sb1, sb2, lane, g, B1w, k);
        #pragma unroll
        for (int i = 0; i < 32; i++) zf[i] = fmaf(h6, k[i], z[i]);

        packB1_axpy(z, k, 0.5f * h, B1w);
        feval(sA1, sA2, sb1, sb2, lane, g, B1w, k);          // k2
        #pragma unroll
        for (int i = 0; i < 32; i++) zf[i] = fmaf(h3, k[i], zf[i]);

        packB1_axpy(z, k, 0.5f * h, B1w);
        feval(sA1, sA2, sb1, sb2, lane, g, B1w, k);          // k3
        #pragma unroll
        for (int i = 0; i < 32; i++) zf[i] = fmaf(h3, k[i], zf[i]);

        packB1_axpy(z, k, h, B1w);
        feval(sA1, sA2, sb1, sb2, lane, g, B1w, k);          // k4
        #pragma unroll
        for (int i = 0; i < 32; i++) z[i] = fmaf(h6, k[i], zf[i]);

        // ---- store trajectory[s+1] via per-wave LDS transpose ----
        asm volatile("s_waitcnt lgkmcnt(0)" ::: "memory");
        #pragma unroll
        for (int mt = 0; mt < 2; mt++)
            #pragma unroll
            for (int rp = 0; rp < 8; rp++) {
                int d    = mt * 32 + (rp & 1) * 2 + 8 * (rp >> 1) + 4 * g;
                int byte = ln31 * 256 + d * 4;
                float2 v = make_float2(z[mt * 16 + rp * 2], z[mt * 16 + rp * 2 + 1]);
                *reinterpret_cast<float2*>((char*)tb + (byte ^ ((ln31 & 7) << 4))) = v;
            }
        asm volatile("s_waitcnt lgkmcnt(0)" ::: "memory");
        float* obase = out + ((size_t)(s + 1) * BS + rowbase) * DIM;
        #pragma unroll
        for (int p = 0; p < 8; p++) {
            int batch  = (lane >> 4) + 4 * p;
            int linear = lane * 16 + p * 1024;
            float4 v = *reinterpret_cast<float4*>((char*)tb + (linear ^ ((batch & 7) << 4)));
            *reinterpret_cast<float4*>(obase + batch * DIM + (lane & 15) * 4) = v;
        }
    }
}

extern "C" void kernel_launch(void* const* d_in, const int* in_sizes, int n_in,
                              void* d_out, int out_size, void* d_ws, size_t ws_size,
                              hipStream_t stream) {
    const float* z0 = (const float*)d_in[0];
    const float* t  = (const float*)d_in[1];
    const float* W1 = (const float*)d_in[2];
    const float* b1 = (const float*)d_in[3];
    const float* W2 = (const float*)d_in[4];
    const float* b2 = (const float*)d_in[5];
    float* out = (float*)d_out;

    node_mfma_kernel<<<dim3(NBLOCKS), dim3(BLOCK), 0, stream>>>(
        z0, t, W1, b1, W2, b2, out);
}

// Round 5
// 3042.329 us; speedup vs baseline: 2.7096x; 1.0775x over previous
//
#include <hip/hip_runtime.h>

#define DIM   64
#define HID   256
#define TLEN  21
#define BS    65536
#define BLOCK 512
#define WAVES 8
#define ROWS_PER_WAVE 32
#define ROWS_PER_BLOCK 256
#define NBLOCKS (BS / ROWS_PER_BLOCK)   // 256

typedef __bf16 bf16x8 __attribute__((ext_vector_type(8)));
typedef float  f32x16 __attribute__((ext_vector_type(16)));

union U128 { uint4 u; bf16x8 b; };
__device__ __forceinline__ bf16x8 as_bf16x8(uint4 u) { U128 t; t.u = u; return t.b; }

__device__ __forceinline__ unsigned pack2(float a, float b) {
    __bf16 x = (__bf16)a, y = (__bf16)b;
    unsigned short ux = __builtin_bit_cast(unsigned short, x);
    unsigned short uy = __builtin_bit_cast(unsigned short, y);
    return (unsigned)ux | ((unsigned)uy << 16);
}

// tanh(x) = 1 - 2/(e^{2x}+1). Saturates correctly through exp overflow.
__device__ __forceinline__ float tanh_f(float x) {
    float e = __expf(2.0f * x);
    return 1.0f - __fdividef(2.0f, e + 1.0f);
}

__device__ __forceinline__ uint4 pack_lo(f32x16 v) {
    return make_uint4(pack2(v[0], v[1]), pack2(v[2], v[3]),
                      pack2(v[4], v[5]), pack2(v[6], v[7]));
}
__device__ __forceinline__ uint4 pack_hi(f32x16 v) {
    return make_uint4(pack2(v[8], v[9]),  pack2(v[10], v[11]),
                      pack2(v[12], v[13]), pack2(v[14], v[15]));
}
__device__ __forceinline__ f32x16 axpy16(float c, f32x16 k, f32x16 z) {
    f32x16 r;
    #pragma unroll
    for (int i = 0; i < 16; i++) r[i] = fmaf(c, k[i], z[i]);
    return r;
}

struct KOut { f32x16 a, b; };

// ---------------------------------------------------------------------------
// Fragment conventions (mfma_f32_32x32x16_bf16, swapped chain) — verified
// (absmax 0.031):
//   matmul1: D1[hid][batch] = A1(W1T) * B1(ztT)   (K = dim, 4 k-tiles)
//   matmul2: D2[dim][batch] = A2(W2T) * B2(tanhT) (K = hid, 16 k-tiles)
// C/D layout: col = lane&31, row_local = (r&3) + 8*(r>>2) + 4*(lane>>5).
// B-frag k->physical map P(g,j) = 4g + (j&3) + 8*(j>>2) so frag word i =
// pack2(x[2i], x[2i+1]) in C/D register order; weights pre-permuted in LDS.
//
// Round-5 change: ALL thread-private state is named ext_vector values
// (f32x16 / uint4) — no C arrays, no pointer-passing of privates. Rounds
// 2-4's ~10 GB HBM traffic was private arrays living in scratch (launch-
// bounds-invariant, VGPR=128 both at (512,1) and (512,2) => not a regalloc
// cap). By-construction register residency.
// ---------------------------------------------------------------------------

__device__ __forceinline__ KOut feval(const uint4* A1, const uint4* A2,
                                      const float4* b1q, const float4* b2q,
                                      int lane, int g,
                                      uint4 bk0, uint4 bk1, uint4 bk2, uint4 bk3)
{
    f32x16 d2a, d2b;
    #pragma unroll
    for (int q = 0; q < 4; q++) {                  // C-in = b2 fragments
        float4 ba = b2q[(0 + g) * 4 + q];
        float4 bb = b2q[(2 + g) * 4 + q];
        d2a[q * 4 + 0] = ba.x; d2a[q * 4 + 1] = ba.y;
        d2a[q * 4 + 2] = ba.z; d2a[q * 4 + 3] = ba.w;
        d2b[q * 4 + 0] = bb.x; d2b[q * 4 + 1] = bb.y;
        d2b[q * 4 + 2] = bb.z; d2b[q * 4 + 3] = bb.w;
    }

    #pragma unroll
    for (int ht = 0; ht < 8; ht++) {
        f32x16 d1;
        #pragma unroll
        for (int q = 0; q < 4; q++) {              // C-in = b1 fragment
            float4 bq = b1q[(ht * 2 + g) * 4 + q];
            d1[q * 4 + 0] = bq.x; d1[q * 4 + 1] = bq.y;
            d1[q * 4 + 2] = bq.z; d1[q * 4 + 3] = bq.w;
        }
        d1 = __builtin_amdgcn_mfma_f32_32x32x16_bf16(
                 as_bf16x8(A1[(ht * 4 + 0) * 64 + lane]), as_bf16x8(bk0), d1, 0, 0, 0);
        d1 = __builtin_amdgcn_mfma_f32_32x32x16_bf16(
                 as_bf16x8(A1[(ht * 4 + 1) * 64 + lane]), as_bf16x8(bk1), d1, 0, 0, 0);
        d1 = __builtin_amdgcn_mfma_f32_32x32x16_bf16(
                 as_bf16x8(A1[(ht * 4 + 2) * 64 + lane]), as_bf16x8(bk2), d1, 0, 0, 0);
        d1 = __builtin_amdgcn_mfma_f32_32x32x16_bf16(
                 as_bf16x8(A1[(ht * 4 + 3) * 64 + lane]), as_bf16x8(bk3), d1, 0, 0, 0);

        uint4 lo = make_uint4(pack2(tanh_f(d1[0]), tanh_f(d1[1])),
                              pack2(tanh_f(d1[2]), tanh_f(d1[3])),
                              pack2(tanh_f(d1[4]), tanh_f(d1[5])),
                              pack2(tanh_f(d1[6]), tanh_f(d1[7])));
        uint4 hi = make_uint4(pack2(tanh_f(d1[8]),  tanh_f(d1[9])),
                              pack2(tanh_f(d1[10]), tanh_f(d1[11])),
                              pack2(tanh_f(d1[12]), tanh_f(d1[13])),
                              pack2(tanh_f(d1[14]), tanh_f(d1[15])));

        d2a = __builtin_amdgcn_mfma_f32_32x32x16_bf16(
                  as_bf16x8(A2[(2 * ht) * 64 + lane]), as_bf16x8(lo), d2a, 0, 0, 0);
        d2b = __builtin_amdgcn_mfma_f32_32x32x16_bf16(
                  as_bf16x8(A2[(16 + 2 * ht) * 64 + lane]), as_bf16x8(lo), d2b, 0, 0, 0);
        d2a = __builtin_amdgcn_mfma_f32_32x32x16_bf16(
                  as_bf16x8(A2[(2 * ht + 1) * 64 + lane]), as_bf16x8(hi), d2a, 0, 0, 0);
        d2b = __builtin_amdgcn_mfma_f32_32x32x16_bf16(
                  as_bf16x8(A2[(16 + 2 * ht + 1) * 64 + lane]), as_bf16x8(hi), d2b, 0, 0, 0);
    }

    KOut r; r.a = d2a; r.b = d2b; return r;
}

extern "C" __global__ __launch_bounds__(BLOCK, 2) void node_mfma_kernel(
    const float* __restrict__ z0, const float* __restrict__ tarr,
    const float* __restrict__ W1, const float* __restrict__ b1,
    const float* __restrict__ W2, const float* __restrict__ b2,
    float* __restrict__ out)
{
    __shared__ __align__(16) unsigned short sA1[32 * 64 * 8];  // 32 KiB
    __shared__ __align__(16) unsigned short sA2[32 * 64 * 8];  // 32 KiB
    __shared__ __align__(16) float sb1[8 * 2 * 16];
    __shared__ __align__(16) float sb2[2 * 2 * 16];
    __shared__ __align__(16) float trbuf[WAVES][2048];         // 8 KiB per wave

    const int tid  = threadIdx.x;
    const int lane = tid & 63;
    const int wv   = tid >> 6;
    const int g    = lane >> 5;
    const int ln31 = lane & 31;

    // ---- stage W1 fragments: coalesced global reads, scattered LDS writes ----
    for (int idx = tid; idx < DIM * HID; idx += BLOCK) {
        int hid = idx & (HID - 1);
        int dim = idx >> 8;
        int c   = hid & 31, ht = hid >> 5;
        int j   = (dim & 3) | (((dim >> 3) & 1) << 2);
        int gg  = (dim >> 2) & 1;
        int kt  = dim >> 4;
        __bf16 bv = (__bf16)W1[idx];
        sA1[((ht * 4 + kt) * 64 + gg * 32 + c) * 8 + j] =
            __builtin_bit_cast(unsigned short, bv);
    }
    // ---- stage W2 fragments ----
    for (int idx = tid; idx < HID * DIM; idx += BLOCK) {
        int dim = idx & 63;
        int hid = idx >> 6;
        int c   = dim & 31, mt = dim >> 5;
        int hlo = hid & 15;
        int j   = (hlo & 3) | (((hlo >> 3) & 1) << 2);
        int gg  = (hlo >> 2) & 1;
        int kt2 = hid >> 4;
        __bf16 bv = (__bf16)W2[idx];
        sA2[((mt * 16 + kt2) * 64 + gg * 32 + c) * 8 + j] =
            __builtin_bit_cast(unsigned short, bv);
    }
    // ---- biases, permuted to C/D reg order ----
    if (tid < 256) {
        int r = tid & 15, gg = (tid >> 4) & 1, ht = tid >> 5;
        sb1[tid] = b1[ht * 32 + (r & 3) + 8 * (r >> 2) + 4 * gg];
    }
    if (tid < 64) {
        int r = tid & 15, gg = (tid >> 4) & 1, mt = tid >> 5;
        sb2[tid] = b2[mt * 32 + (r & 3) + 8 * (r >> 2) + 4 * gg];
    }

    // ---- out[0] = z0 (coalesced block-slice copy) ----
    {
        const float4* src = reinterpret_cast<const float4*>(z0 + (size_t)blockIdx.x * ROWS_PER_BLOCK * DIM);
        float4*       dst = reinterpret_cast<float4*>(out + (size_t)blockIdx.x * ROWS_PER_BLOCK * DIM);
        for (int i = tid; i < ROWS_PER_BLOCK * DIM / 4; i += BLOCK) dst[i] = src[i];
    }

    __syncthreads();

    const int rowbase = blockIdx.x * ROWS_PER_BLOCK + wv * ROWS_PER_WAVE;
    float* tb = trbuf[wv];

    const uint4*  A1  = reinterpret_cast<const uint4*>(sA1);
    const uint4*  A2  = reinterpret_cast<const uint4*>(sA2);
    const float4* b1q = reinterpret_cast<const float4*>(sb1);
    const float4* b2q = reinterpret_cast<const float4*>(sb2);

    // ---- z0 -> registers via per-wave LDS transpose (XOR-swizzled 16B) ----
    #pragma unroll
    for (int p = 0; p < 8; p++) {
        int batch  = (lane >> 4) + 4 * p;
        int linear = lane * 16 + p * 1024;
        float4 v = *reinterpret_cast<const float4*>(
            z0 + (size_t)(rowbase + batch) * DIM + (lane & 15) * 4);
        *reinterpret_cast<float4*>((char*)tb + (linear ^ ((batch & 7) << 4))) = v;
    }
    asm volatile("s_waitcnt lgkmcnt(0)" ::: "memory");

    f32x16 za, zb;
    #pragma unroll
    for (int rp = 0; rp < 8; rp++) {
        int d    = (rp & 1) * 2 + 8 * (rp >> 1) + 4 * g;    // r = 2*rp, mt=0
        int byte = ln31 * 256 + d * 4;
        float2 v = *reinterpret_cast<float2*>((char*)tb + (byte ^ ((ln31 & 7) << 4)));
        za[2 * rp] = v.x; za[2 * rp + 1] = v.y;
    }
    #pragma unroll
    for (int rp = 0; rp < 8; rp++) {
        int d    = 32 + (rp & 1) * 2 + 8 * (rp >> 1) + 4 * g;  // mt=1
        int byte = ln31 * 256 + d * 4;
        float2 v = *reinterpret_cast<float2*>((char*)tb + (byte ^ ((ln31 & 7) << 4)));
        zb[2 * rp] = v.x; zb[2 * rp + 1] = v.y;
    }

    for (int s = 0; s < TLEN - 1; s++) {
        const float h  = tarr[s + 1] - tarr[s];
        const float h2 = 0.5f * h;
        const float h3 = h * (1.0f / 3.0f);
        const float h6 = h * (1.0f / 6.0f);

        KOut k1 = feval(A1, A2, b1q, b2q, lane, g,
                        pack_lo(za), pack_hi(za), pack_lo(zb), pack_hi(zb));
        f32x16 zfa = axpy16(h6, k1.a, za), zfb = axpy16(h6, k1.b, zb);
        f32x16 pa  = axpy16(h2, k1.a, za), pb  = axpy16(h2, k1.b, zb);

        KOut k2 = feval(A1, A2, b1q, b2q, lane, g,
                        pack_lo(pa), pack_hi(pa), pack_lo(pb), pack_hi(pb));
        zfa = axpy16(h3, k2.a, zfa); zfb = axpy16(h3, k2.b, zfb);
        pa  = axpy16(h2, k2.a, za);  pb  = axpy16(h2, k2.b, zb);

        KOut k3 = feval(A1, A2, b1q, b2q, lane, g,
                        pack_lo(pa), pack_hi(pa), pack_lo(pb), pack_hi(pb));
        zfa = axpy16(h3, k3.a, zfa); zfb = axpy16(h3, k3.b, zfb);
        pa  = axpy16(h, k3.a, za);   pb  = axpy16(h, k3.b, zb);

        KOut k4 = feval(A1, A2, b1q, b2q, lane, g,
                        pack_lo(pa), pack_hi(pa), pack_lo(pb), pack_hi(pb));
        za = axpy16(h6, k4.a, zfa);  zb = axpy16(h6, k4.b, zfb);

        // ---- store trajectory[s+1] via per-wave LDS transpose ----
        asm volatile("s_waitcnt lgkmcnt(0)" ::: "memory");
        #pragma unroll
        for (int rp = 0; rp < 8; rp++) {
            int d    = (rp & 1) * 2 + 8 * (rp >> 1) + 4 * g;
            int byte = ln31 * 256 + d * 4;
            *reinterpret_cast<float2*>((char*)tb + (byte ^ ((ln31 & 7) << 4))) =
                make_float2(za[2 * rp], za[2 * rp + 1]);
        }
        #pragma unroll
        for (int rp = 0; rp < 8; rp++) {
            int d    = 32 + (rp & 1) * 2 + 8 * (rp >> 1) + 4 * g;
            int byte = ln31 * 256 + d * 4;
            *reinterpret_cast<float2*>((char*)tb + (byte ^ ((ln31 & 7) << 4))) =
                make_float2(zb[2 * rp], zb[2 * rp + 1]);
        }
        asm volatile("s_waitcnt lgkmcnt(0)" ::: "memory");
        float* obase = out + ((size_t)(s + 1) * BS + rowbase) * DIM;
        #pragma unroll
        for (int p = 0; p < 8; p++) {
            int batch  = (lane >> 4) + 4 * p;
            int linear = lane * 16 + p * 1024;
            float4 v = *reinterpret_cast<float4*>((char*)tb + (linear ^ ((batch & 7) << 4)));
            *reinterpret_cast<float4*>(obase + batch * DIM + (lane & 15) * 4) = v;
        }
    }
}

extern "C" void kernel_launch(void* const* d_in, const int* in_sizes, int n_in,
                              void* d_out, int out_size, void* d_ws, size_t ws_size,
                              hipStream_t stream) {
    const float* z0 = (const float*)d_in[0];
    const float* t  = (const float*)d_in[1];
    const float* W1 = (const float*)d_in[2];
    const float* b1 = (const float*)d_in[3];
    const float* W2 = (const float*)d_in[4];
    const float* b2 = (const float*)d_in[5];
    float* out = (float*)d_out;

    node_mfma_kernel<<<dim3(NBLOCKS), dim3(BLOCK), 0, stream>>>(
        z0, t, W1, b1, W2, b2, out);
}

// Round 6
// 2629.544 us; speedup vs baseline: 3.1349x; 1.1570x over previous
//
#include <hip/hip_runtime.h>

#define DIM   64
#define HID   256
#define TLEN  21
#define BS    65536
#define BLOCK 512
#define WAVES 8
#define ROWS_PER_WAVE 32
#define ROWS_PER_BLOCK 256
#define NBLOCKS (BS / ROWS_PER_BLOCK)   // 256

typedef __bf16    bf16x8  __attribute__((ext_vector_type(8)));
typedef float     f32x16  __attribute__((ext_vector_type(16)));
typedef float     f32x4   __attribute__((ext_vector_type(4)));
typedef float     f32x2   __attribute__((ext_vector_type(2)));
typedef unsigned  uint32x4 __attribute__((ext_vector_type(4)));

// Pure SSA bitcast — NO union type-punning (unions can materialize stack
// slots; suspected source of rounds 2-5's ~10 GB scratch HBM traffic).
__device__ __forceinline__ bf16x8 as_bf16x8(uint32x4 u) {
    return __builtin_bit_cast(bf16x8, u);
}

__device__ __forceinline__ unsigned pack2(float a, float b) {
    __bf16 x = (__bf16)a, y = (__bf16)b;
    unsigned short ux = __builtin_bit_cast(unsigned short, x);
    unsigned short uy = __builtin_bit_cast(unsigned short, y);
    return (unsigned)ux | ((unsigned)uy << 16);
}

// tanh(x) = 1 - 2/(e^{2x}+1). Saturates correctly through exp overflow.
__device__ __forceinline__ float tanh_f(float x) {
    float e = __expf(2.0f * x);
    return 1.0f - __fdividef(2.0f, e + 1.0f);
}

__device__ __forceinline__ uint32x4 pack_lo(f32x16 v) {
    uint32x4 r;
    r[0] = pack2(v[0], v[1]); r[1] = pack2(v[2], v[3]);
    r[2] = pack2(v[4], v[5]); r[3] = pack2(v[6], v[7]);
    return r;
}
__device__ __forceinline__ uint32x4 pack_hi(f32x16 v) {
    uint32x4 r;
    r[0] = pack2(v[8], v[9]);   r[1] = pack2(v[10], v[11]);
    r[2] = pack2(v[12], v[13]); r[3] = pack2(v[14], v[15]);
    return r;
}
__device__ __forceinline__ f32x16 axpy16(float c, f32x16 k, f32x16 z) {
    f32x16 r;
    #pragma unroll
    for (int i = 0; i < 16; i++) r[i] = fmaf(c, k[i], z[i]);
    return r;
}

struct KOut { f32x16 a, b; };

// ---------------------------------------------------------------------------
// Fragment conventions (mfma_f32_32x32x16_bf16, swapped chain) — verified
// (absmax 0.031):
//   matmul1: D1[hid][batch] = A1(W1T) * B1(ztT)   (K = dim, 4 k-tiles)
//   matmul2: D2[dim][batch] = A2(W2T) * B2(tanhT) (K = hid, 16 k-tiles)
// C/D layout: col = lane&31, row_local = (r&3) + 8*(r>>2) + 4*(lane>>5).
// B-frag k->physical map P(g,j) = 4g + (j&3) + 8*(j>>2) so frag word i =
// pack2(x[2i], x[2i+1]) in C/D register order; weights pre-permuted in LDS.
//
// Round-6: alloca elimination — __builtin_bit_cast instead of union U128,
// ext_vector types everywhere in the hot path (no uint4/float4/float2
// structs), no asm volatile "memory" barriers (compiler handles DS ordering
// and waitcnts for its own loads/stores).
// ---------------------------------------------------------------------------

__device__ __forceinline__ KOut feval(const uint32x4* A1, const uint32x4* A2,
                                      const f32x4* b1q, const f32x4* b2q,
                                      int lane, int g,
                                      uint32x4 bk0, uint32x4 bk1,
                                      uint32x4 bk2, uint32x4 bk3)
{
    f32x16 d2a, d2b;
    #pragma unroll
    for (int q = 0; q < 4; q++) {                  // C-in = b2 fragments
        f32x4 ba = b2q[(0 + g) * 4 + q];
        f32x4 bb = b2q[(2 + g) * 4 + q];
        #pragma unroll
        for (int i = 0; i < 4; i++) { d2a[q * 4 + i] = ba[i]; d2b[q * 4 + i] = bb[i]; }
    }

    #pragma unroll
    for (int ht = 0; ht < 8; ht++) {
        f32x16 d1;
        #pragma unroll
        for (int q = 0; q < 4; q++) {              // C-in = b1 fragment
            f32x4 bq = b1q[(ht * 2 + g) * 4 + q];
            #pragma unroll
            for (int i = 0; i < 4; i++) d1[q * 4 + i] = bq[i];
        }
        d1 = __builtin_amdgcn_mfma_f32_32x32x16_bf16(
                 as_bf16x8(A1[(ht * 4 + 0) * 64 + lane]), as_bf16x8(bk0), d1, 0, 0, 0);
        d1 = __builtin_amdgcn_mfma_f32_32x32x16_bf16(
                 as_bf16x8(A1[(ht * 4 + 1) * 64 + lane]), as_bf16x8(bk1), d1, 0, 0, 0);
        d1 = __builtin_amdgcn_mfma_f32_32x32x16_bf16(
                 as_bf16x8(A1[(ht * 4 + 2) * 64 + lane]), as_bf16x8(bk2), d1, 0, 0, 0);
        d1 = __builtin_amdgcn_mfma_f32_32x32x16_bf16(
                 as_bf16x8(A1[(ht * 4 + 3) * 64 + lane]), as_bf16x8(bk3), d1, 0, 0, 0);

        uint32x4 lo, hi;
        lo[0] = pack2(tanh_f(d1[0]),  tanh_f(d1[1]));
        lo[1] = pack2(tanh_f(d1[2]),  tanh_f(d1[3]));
        lo[2] = pack2(tanh_f(d1[4]),  tanh_f(d1[5]));
        lo[3] = pack2(tanh_f(d1[6]),  tanh_f(d1[7]));
        hi[0] = pack2(tanh_f(d1[8]),  tanh_f(d1[9]));
        hi[1] = pack2(tanh_f(d1[10]), tanh_f(d1[11]));
        hi[2] = pack2(tanh_f(d1[12]), tanh_f(d1[13]));
        hi[3] = pack2(tanh_f(d1[14]), tanh_f(d1[15]));

        d2a = __builtin_amdgcn_mfma_f32_32x32x16_bf16(
                  as_bf16x8(A2[(2 * ht) * 64 + lane]), as_bf16x8(lo), d2a, 0, 0, 0);
        d2b = __builtin_amdgcn_mfma_f32_32x32x16_bf16(
                  as_bf16x8(A2[(16 + 2 * ht) * 64 + lane]), as_bf16x8(lo), d2b, 0, 0, 0);
        d2a = __builtin_amdgcn_mfma_f32_32x32x16_bf16(
                  as_bf16x8(A2[(2 * ht + 1) * 64 + lane]), as_bf16x8(hi), d2a, 0, 0, 0);
        d2b = __builtin_amdgcn_mfma_f32_32x32x16_bf16(
                  as_bf16x8(A2[(16 + 2 * ht + 1) * 64 + lane]), as_bf16x8(hi), d2b, 0, 0, 0);
    }

    return KOut{d2a, d2b};
}

extern "C" __global__ __launch_bounds__(BLOCK, 2) void node_mfma_kernel(
    const float* __restrict__ z0, const float* __restrict__ tarr,
    const float* __restrict__ W1, const float* __restrict__ b1,
    const float* __restrict__ W2, const float* __restrict__ b2,
    float* __restrict__ out)
{
    __shared__ __align__(16) unsigned short sA1[32 * 64 * 8];  // 32 KiB
    __shared__ __align__(16) unsigned short sA2[32 * 64 * 8];  // 32 KiB
    __shared__ __align__(16) float sb1[8 * 2 * 16];
    __shared__ __align__(16) float sb2[2 * 2 * 16];
    __shared__ __align__(16) float trbuf[WAVES][2048];         // 8 KiB per wave

    const int tid  = threadIdx.x;
    const int lane = tid & 63;
    const int wv   = tid >> 6;
    const int g    = lane >> 5;
    const int ln31 = lane & 31;

    // ---- stage W1 fragments: coalesced global reads, scattered LDS writes ----
    for (int idx = tid; idx < DIM * HID; idx += BLOCK) {
        int hid = idx & (HID - 1);
        int dim = idx >> 8;
        int c   = hid & 31, ht = hid >> 5;
        int j   = (dim & 3) | (((dim >> 3) & 1) << 2);
        int gg  = (dim >> 2) & 1;
        int kt  = dim >> 4;
        __bf16 bv = (__bf16)W1[idx];
        sA1[((ht * 4 + kt) * 64 + gg * 32 + c) * 8 + j] =
            __builtin_bit_cast(unsigned short, bv);
    }
    // ---- stage W2 fragments ----
    for (int idx = tid; idx < HID * DIM; idx += BLOCK) {
        int dim = idx & 63;
        int hid = idx >> 6;
        int c   = dim & 31, mt = dim >> 5;
        int hlo = hid & 15;
        int j   = (hlo & 3) | (((hlo >> 3) & 1) << 2);
        int gg  = (hlo >> 2) & 1;
        int kt2 = hid >> 4;
        __bf16 bv = (__bf16)W2[idx];
        sA2[((mt * 16 + kt2) * 64 + gg * 32 + c) * 8 + j] =
            __builtin_bit_cast(unsigned short, bv);
    }
    // ---- biases, permuted to C/D reg order ----
    if (tid < 256) {
        int r = tid & 15, gg = (tid >> 4) & 1, ht = tid >> 5;
        sb1[tid] = b1[ht * 32 + (r & 3) + 8 * (r >> 2) + 4 * gg];
    }
    if (tid < 64) {
        int r = tid & 15, gg = (tid >> 4) & 1, mt = tid >> 5;
        sb2[tid] = b2[mt * 32 + (r & 3) + 8 * (r >> 2) + 4 * gg];
    }

    // ---- out[0] = z0 (coalesced block-slice copy) ----
    {
        const f32x4* src = reinterpret_cast<const f32x4*>(z0 + (size_t)blockIdx.x * ROWS_PER_BLOCK * DIM);
        f32x4*       dst = reinterpret_cast<f32x4*>(out + (size_t)blockIdx.x * ROWS_PER_BLOCK * DIM);
        for (int i = tid; i < ROWS_PER_BLOCK * DIM / 4; i += BLOCK) dst[i] = src[i];
    }

    __syncthreads();

    const int rowbase = blockIdx.x * ROWS_PER_BLOCK + wv * ROWS_PER_WAVE;
    float* tb = trbuf[wv];

    const uint32x4* A1  = reinterpret_cast<const uint32x4*>(sA1);
    const uint32x4* A2  = reinterpret_cast<const uint32x4*>(sA2);
    const f32x4*    b1q = reinterpret_cast<const f32x4*>(sb1);
    const f32x4*    b2q = reinterpret_cast<const f32x4*>(sb2);

    // ---- z0 -> registers via per-wave LDS transpose (XOR-swizzled 16B) ----
    #pragma unroll
    for (int p = 0; p < 8; p++) {
        int batch  = (lane >> 4) + 4 * p;
        int linear = lane * 16 + p * 1024;
        f32x4 v = *reinterpret_cast<const f32x4*>(
            z0 + (size_t)(rowbase + batch) * DIM + (lane & 15) * 4);
        *reinterpret_cast<f32x4*>((char*)tb + (linear ^ ((batch & 7) << 4))) = v;
    }

    f32x16 za, zb;
    #pragma unroll
    for (int rp = 0; rp < 8; rp++) {
        int d    = (rp & 1) * 2 + 8 * (rp >> 1) + 4 * g;    // r = 2*rp, mt=0
        int byte = ln31 * 256 + d * 4;
        f32x2 v = *reinterpret_cast<f32x2*>((char*)tb + (byte ^ ((ln31 & 7) << 4)));
        za[2 * rp] = v[0]; za[2 * rp + 1] = v[1];
    }
    #pragma unroll
    for (int rp = 0; rp < 8; rp++) {
        int d    = 32 + (rp & 1) * 2 + 8 * (rp >> 1) + 4 * g;  // mt=1
        int byte = ln31 * 256 + d * 4;
        f32x2 v = *reinterpret_cast<f32x2*>((char*)tb + (byte ^ ((ln31 & 7) << 4)));
        zb[2 * rp] = v[0]; zb[2 * rp + 1] = v[1];
    }

    #pragma unroll 1
    for (int s = 0; s < TLEN - 1; s++) {
        const float h  = tarr[s + 1] - tarr[s];
        const float h2 = 0.5f * h;
        const float h3 = h * (1.0f / 3.0f);
        const float h6 = h * (1.0f / 6.0f);

        KOut k1 = feval(A1, A2, b1q, b2q, lane, g,
                        pack_lo(za), pack_hi(za), pack_lo(zb), pack_hi(zb));
        f32x16 zfa = axpy16(h6, k1.a, za), zfb = axpy16(h6, k1.b, zb);
        f32x16 pa  = axpy16(h2, k1.a, za), pb  = axpy16(h2, k1.b, zb);

        KOut k2 = feval(A1, A2, b1q, b2q, lane, g,
                        pack_lo(pa), pack_hi(pa), pack_lo(pb), pack_hi(pb));
        zfa = axpy16(h3, k2.a, zfa); zfb = axpy16(h3, k2.b, zfb);
        pa  = axpy16(h2, k2.a, za);  pb  = axpy16(h2, k2.b, zb);

        KOut k3 = feval(A1, A2, b1q, b2q, lane, g,
                        pack_lo(pa), pack_hi(pa), pack_lo(pb), pack_hi(pb));
        zfa = axpy16(h3, k3.a, zfa); zfb = axpy16(h3, k3.b, zfb);
        pa  = axpy16(h, k3.a, za);   pb  = axpy16(h, k3.b, zb);

        KOut k4 = feval(A1, A2, b1q, b2q, lane, g,
                        pack_lo(pa), pack_hi(pa), pack_lo(pb), pack_hi(pb));
        za = axpy16(h6, k4.a, zfa);  zb = axpy16(h6, k4.b, zfb);

        // ---- store trajectory[s+1] via per-wave LDS transpose ----
        #pragma unroll
        for (int rp = 0; rp < 8; rp++) {
            int d    = (rp & 1) * 2 + 8 * (rp >> 1) + 4 * g;
            int byte = ln31 * 256 + d * 4;
            f32x2 v; v[0] = za[2 * rp]; v[1] = za[2 * rp + 1];
            *reinterpret_cast<f32x2*>((char*)tb + (byte ^ ((ln31 & 7) << 4))) = v;
        }
        #pragma unroll
        for (int rp = 0; rp < 8; rp++) {
            int d    = 32 + (rp & 1) * 2 + 8 * (rp >> 1) + 4 * g;
            int byte = ln31 * 256 + d * 4;
            f32x2 v; v[0] = zb[2 * rp]; v[1] = zb[2 * rp + 1];
            *reinterpret_cast<f32x2*>((char*)tb + (byte ^ ((ln31 & 7) << 4))) = v;
        }
        float* obase = out + ((size_t)(s + 1) * BS + rowbase) * DIM;
        #pragma unroll
        for (int p = 0; p < 8; p++) {
            int batch  = (lane >> 4) + 4 * p;
            int linear = lane * 16 + p * 1024;
            f32x4 v = *reinterpret_cast<f32x4*>((char*)tb + (linear ^ ((batch & 7) << 4)));
            *reinterpret_cast<f32x4*>(obase + batch * DIM + (lane & 15) * 4) = v;
        }
    }
}

extern "C" void kernel_launch(void* const* d_in, const int* in_sizes, int n_in,
                              void* d_out, int out_size, void* d_ws, size_t ws_size,
                              hipStream_t stream) {
    const float* z0 = (const float*)d_in[0];
    const float* t  = (const float*)d_in[1];
    const float* W1 = (const float*)d_in[2];
    const float* b1 = (const float*)d_in[3];
    const float* W2 = (const float*)d_in[4];
    const float* b2 = (const float*)d_in[5];
    float* out = (float*)d_out;

    node_mfma_kernel<<<dim3(NBLOCKS), dim3(BLOCK), 0, stream>>>(
        z0, t, W1, b1, W2, b2, out);
}